// Round 14
// baseline (170.312 us; speedup 1.0000x reference)
//
#include <hip/hip_runtime.h>
#include <math.h>

#define T_LEN      24000
#define W_LEN      81
#define HALF_W     40
#define NK         21
#define MAXORD     10
#define NIMG_TOTAL 1561
#define NROUNDS    25
#define FS_F       48000.0f
#define C_F        343.0f
#define FS_OVER_C  (48000.0f / 343.0f)
#define PI_F       3.14159265358979323846f
#define INV_4PI_F  0.07957747154594767f
#define LOG2_BETA  (-0.15200309344504997f)   // log2(0.9)
#define NEG_SLOPE  0.01f
#define NTHREADS   1024

// LDS: rir 24000 + dsq 64 + mlp 96 = 24160 floats = 96640 B (needs gfx950 160K)
#define SMEM_FLOATS (T_LEN + 64 + 96)
#define SMEM_BYTES  (SMEM_FLOATS * 4)

// ---- compile-time table of valid image triples ----
// entry: (order << 15) | (kxi << 10) | (kyi << 5) | kzi
struct Table { unsigned int e[NIMG_TOTAL]; };
constexpr Table make_table() {
    Table t{};
    int n = 0;
    for (int kx = 0; kx < NK; ++kx)
        for (int ky = 0; ky < NK; ++ky)
            for (int kz = 0; kz < NK; ++kz) {
                int ax = kx >= MAXORD ? kx - MAXORD : MAXORD - kx;
                int ay = ky >= MAXORD ? ky - MAXORD : MAXORD - ky;
                int az = kz >= MAXORD ? kz - MAXORD : MAXORD - kz;
                int order = ax + ay + az;
                if (order <= MAXORD)
                    t.e[n++] = (unsigned)((order << 15) | (kx << 10) | (ky << 5) | kz);
            }
    return t;
}
__constant__ Table g_tbl = make_table();

__global__ __launch_bounds__(NTHREADS)
void rir_lpi_kernel(const float* __restrict__ g_in,
                    const float* __restrict__ W1, const float* __restrict__ b1,
                    const float* __restrict__ W2, const float* __restrict__ b2,
                    const float* __restrict__ W3, const float* __restrict__ b3,
                    float* __restrict__ out_rir, float* __restrict__ out_origin)
{
    extern __shared__ float smem[];
    float* rir   = smem;                 // 24000
    float* dsq   = smem + T_LEN;         // 63 (+1 pad)
    float* sm_in = dsq + 64;             // 22 (+2)
    float* h1    = sm_in + 24;           // 30
    float* h2    = h1 + 30;              // 20
    float* zb    = h2 + 20;              // 9
    float* rms   = zb + 9;               // 9

    const int tid = threadIdx.x;
    const int b   = blockIdx.x;

    // ---- zero the row accumulator (6000 float4 over 1024 threads) ----
    float4* rir4 = (float4*)rir;
    #pragma unroll
    for (int i = tid; i < T_LEN / 4; i += NTHREADS)
        rir4[i] = make_float4(0.f, 0.f, 0.f, 0.f);

    // ---- wave 0: MLP + geometry (in-wave LDS ordering) ----
    if (tid < 64) {
        if (tid < 22) sm_in[tid] = g_in[b * 22 + tid];
        if (tid < 30) {
            float a = b1[tid];
            const float* wp = W1 + tid * 22;
            #pragma unroll
            for (int i = 0; i < 22; ++i) a += sm_in[i] * wp[i];
            h1[tid] = (a >= 0.0f) ? a : NEG_SLOPE * a;
        }
        if (tid < 20) {
            float a = b2[tid];
            const float* wp = W2 + tid * 30;
            #pragma unroll
            for (int i = 0; i < 30; ++i) a += h1[i] * wp[i];
            h2[tid] = (a >= 0.0f) ? a : NEG_SLOPE * a;
        }
        if (tid < 9) {
            float a = b3[tid];
            const float* wp = W3 + tid * 20;
            #pragma unroll
            for (int i = 0; i < 20; ++i) a += h2[i] * wp[i];
            zb[tid] = 1.0f / (1.0f + __expf(-a));
        }
        if (tid < 3) {
            float room = zb[tid] * 20.0f;
            rms[tid]     = room;
            rms[3 + tid] = zb[3 + tid] * room;   // mic
            rms[6 + tid] = zb[6 + tid] * room;   // src
        }
        if (tid == 0) {
            float dx = rms[3] - rms[6], dy = rms[4] - rms[7], dz = rms[5] - rms[8];
            out_origin[b] = 40.0f + FS_F * sqrtf(dx * dx + dy * dy + dz * dz) / C_F;
        }
        if (tid < 3 * NK) {
            int a  = tid / NK;
            int kk = (tid - a * NK) - MAXORD;
            float L = rms[a], src = rms[6 + a];
            float img = ((kk & 1) == 0) ? (float)kk * L + src : (float)(kk + 1) * L - src;
            float diff = img - rms[3 + a];
            dsq[tid] = diff * diff;
        }
    }
    __syncthreads();

    // ---- lane-per-image drain: each thread owns <=2 images, loops 81 taps ----
    // All taps independent (xp += pi, sign flip, idx++); no cross-lane ops,
    // no memory reads in the loop; uniform work regardless of time pileup.
    for (int i = tid; i < NIMG_TOTAL; i += NTHREADS) {
        unsigned e = g_tbl.e[i];
        int kzi = e & 31, kyi = (e >> 5) & 31, kxi = (e >> 10) & 31, order = (int)(e >> 15);
        float d     = sqrtf(dsq[kxi] + dsq[NK + kyi] + dsq[2 * NK + kzi]);
        float delay = 40.0f + d * FS_OVER_C;
        float t0f   = floorf(delay);
        int   t0    = (int)t0f;
        if (t0 - HALF_W >= T_LEN) continue;          // window entirely past T

        float amp  = exp2f((float)order * LOG2_BETA) * INV_4PI_F
                     * __builtin_amdgcn_rcpf(fmaxf(d, 0.001f));
        float frac = delay - t0f;

        if (frac == 0.0f) {
            // sinc(n) = delta(n): single center tap (hann[40] = 1)
            if (t0 < T_LEN) atomicAdd(&rir[t0], amp);
            continue;
        }

        float sp  = __sinf(PI_F * frac);
        float pva = -amp * sp;                        // signed amp*sin at j=0 (n=-40 even)
        float xp  = -(40.0f + frac) * PI_F;           // pi*(n - frac) at j=0
        int   idx = t0 - HALF_W;

        #pragma unroll 3
        for (int j = 0; j < W_LEN; ++j) {
            float hj = 0.5f - 0.5f * __cosf((float)j * (2.0f * PI_F / 80.0f)); // wave-uniform
            float sv = pva * __builtin_amdgcn_rcpf(xp);   // amp * sinc(n - frac)
            if ((unsigned)idx < (unsigned)T_LEN)
                atomicAdd(&rir[idx], sv * hj);
            xp  += PI_F;
            pva  = -pva;
            ++idx;
        }
    }
    __syncthreads();

    // ---- coalesced float4 writeback ----
    float4* out4 = (float4*)(out_rir + (size_t)b * T_LEN);
    #pragma unroll
    for (int i = tid; i < T_LEN / 4; i += NTHREADS) out4[i] = rir4[i];
}

extern "C" void kernel_launch(void* const* d_in, const int* in_sizes, int n_in,
                              void* d_out, int out_size, void* d_ws, size_t ws_size,
                              hipStream_t stream) {
    const float* g_in = (const float*)d_in[0];
    const float* W1   = (const float*)d_in[1];
    const float* b1   = (const float*)d_in[2];
    const float* W2   = (const float*)d_in[3];
    const float* b2   = (const float*)d_in[4];
    const float* W3   = (const float*)d_in[5];
    const float* b3   = (const float*)d_in[6];

    const int B = in_sizes[0] / 22;

    float* out_rir    = (float*)d_out;
    float* out_origin = out_rir + (size_t)B * T_LEN;

    (void)hipFuncSetAttribute((const void*)rir_lpi_kernel,
                              hipFuncAttributeMaxDynamicSharedMemorySize,
                              SMEM_BYTES);

    rir_lpi_kernel<<<B, NTHREADS, SMEM_BYTES, stream>>>(
        g_in, W1, b1, W2, b2, W3, b3, out_rir, out_origin);
}

// Round 15
// 131.213 us; speedup vs baseline: 1.2980x; 1.2980x over previous
//
#include <hip/hip_runtime.h>
#include <math.h>

#define T_LEN      24000
#define TS         448           // samples per slice
#define NSLICE     54            // 54*448 = 24192 >= 24000 (slice 53: 256 valid)
#define W_LEN      81
#define HALF_W     40
#define NK         21
#define MAXORD     10
#define NIMG_TOTAL 1561
#define NROUNDS    25            // ceil(1561/64)
#define FS_F       48000.0f
#define C_F        343.0f
#define FS_OVER_C  (48000.0f / 343.0f)
#define PI_F       3.14159265358979323846f
#define INV_4PI_F  0.07957747154594767f
#define LOG2_BETA  (-0.15200309344504997f)   // log2(0.9)
#define NEG_SLOPE  0.01f

// workspace row layout: 32 float2 header (55 int offsets) + 1568 float2 params
#define HDR_F2     32
#define PAR_CAP    1568
#define ROW_F2     (HDR_F2 + PAR_CAP)        // 1600 float2 = 12800 B/row

// ---- compile-time table of valid image triples ----
struct Table { unsigned int e[NROUNDS * 64]; };
constexpr Table make_table() {
    Table t{};
    int n = 0;
    for (int kx = 0; kx < NK; ++kx)
        for (int ky = 0; ky < NK; ++ky)
            for (int kz = 0; kz < NK; ++kz) {
                int ax = kx >= MAXORD ? kx - MAXORD : MAXORD - kx;
                int ay = ky >= MAXORD ? ky - MAXORD : MAXORD - ky;
                int az = kz >= MAXORD ? kz - MAXORD : MAXORD - kz;
                int order = ax + ay + az;
                if (order <= MAXORD)
                    t.e[n++] = (unsigned)((order << 15) | (kx << 10) | (ky << 5) | kz);
            }
    for (int i = n; i < NROUNDS * 64; ++i) t.e[i] = t.e[n - 1];  // pad (masked)
    return t;
}
__constant__ Table g_tbl = make_table();

// One image: broadcast (aU,dU); pure-register tap math, <=2 conflict-free ds_add.
#define PROCESS(aU, dU)                                                        \
    do {                                                                       \
        float t0b  = floorf(dU);                                              \
        float frac = (dU) - t0b;                                              \
        float sp   = __sinf(PI_F * frac);                                     \
        float pv   = sg * sp;                                                 \
        int   idx  = (int)t0b - HALF_W + lane - lo;                           \
        float x1p  = c1p - PI_F * frac;                                       \
        float sv1  = (x1p == 0.0f) ? 1.0f : pv * __builtin_amdgcn_rcpf(x1p);  \
        if ((unsigned)idx < (unsigned)nout)                                   \
            atomicAdd(&rirw[idx], (aU) * sv1 * hw1);                          \
        if (lane < 17) {                                                      \
            int idx2 = idx + 64;                                              \
            float sv2 = pv * __builtin_amdgcn_rcpf(x1p + 64.0f * PI_F);       \
            if ((unsigned)idx2 < (unsigned)nout)                              \
                atomicAdd(&rirw[idx2], (aU) * sv2 * hw2);                     \
        }                                                                      \
    } while (0)

// ============ Kernel 1: per-row MLP + geometry + bin-sorted params ==========
__global__ __launch_bounds__(64)
void rir_prep_kernel(const float* __restrict__ g_in,
                     const float* __restrict__ W1, const float* __restrict__ b1,
                     const float* __restrict__ W2, const float* __restrict__ b2,
                     const float* __restrict__ W3, const float* __restrict__ b3,
                     float2* __restrict__ ws, float* __restrict__ out_origin)
{
    __shared__ float dsq[3 * NK];
    __shared__ float h1[30], h2[20], zb[9], sm_in[22], rms[9];
    __shared__ int counts[NSLICE], offs[NSLICE + 1], cursor[NSLICE];

    const int lane = threadIdx.x;
    const int b    = blockIdx.x;

    if (lane < NSLICE) counts[lane] = 0;

    if (lane < 22) sm_in[lane] = g_in[b * 22 + lane];
    if (lane < 30) {
        float a = b1[lane];
        const float* wp = W1 + lane * 22;
        #pragma unroll
        for (int i = 0; i < 22; ++i) a += sm_in[i] * wp[i];
        h1[lane] = (a >= 0.0f) ? a : NEG_SLOPE * a;
    }
    if (lane < 20) {
        float a = b2[lane];
        const float* wp = W2 + lane * 30;
        #pragma unroll
        for (int i = 0; i < 30; ++i) a += h1[i] * wp[i];
        h2[lane] = (a >= 0.0f) ? a : NEG_SLOPE * a;
    }
    if (lane < 9) {
        float a = b3[lane];
        const float* wp = W3 + lane * 20;
        #pragma unroll
        for (int i = 0; i < 20; ++i) a += h2[i] * wp[i];
        zb[lane] = 1.0f / (1.0f + __expf(-a));
    }
    if (lane < 3) {
        float room = zb[lane] * 20.0f;
        rms[lane]     = room;
        rms[3 + lane] = zb[3 + lane] * room;   // mic
        rms[6 + lane] = zb[6 + lane] * room;   // src
    }
    if (lane == 0) {
        float dx = rms[3] - rms[6], dy = rms[4] - rms[7], dz = rms[5] - rms[8];
        out_origin[b] = 40.0f + FS_F * sqrtf(dx * dx + dy * dy + dz * dz) / C_F;
    }
    if (lane < 3 * NK) {
        int a  = lane / NK;
        int kk = (lane - a * NK) - MAXORD;
        float L = rms[a], src = rms[6 + a];
        float img = ((kk & 1) == 0) ? (float)kk * L + src : (float)(kk + 1) * L - src;
        float diff = img - rms[3 + a];
        dsq[lane] = diff * diff;
    }

    // pass 1: count images per bin (bin = t0/448, clamped)
    for (int r = 0; r < NROUNDS; ++r) {
        int gi = r * 64 + lane;
        unsigned e = g_tbl.e[gi];
        int kzi = e & 31, kyi = (e >> 5) & 31, kxi = (e >> 10) & 31;
        float d   = sqrtf(dsq[kxi] + dsq[NK + kyi] + dsq[2 * NK + kzi]);
        float dly = 40.0f + d * FS_OVER_C;
        int   t0  = (int)floorf(dly);
        bool live = (gi < NIMG_TOTAL) && (t0 - HALF_W < T_LEN);
        if (live) {
            int bin = min(t0 / TS, NSLICE - 1);
            atomicAdd(&counts[bin], 1);
        }
    }

    // serial prefix scan (54 elems, once per row) + cursor init
    if (lane == 0) {
        int acc = 0;
        for (int s = 0; s < NSLICE; ++s) { offs[s] = acc; acc += counts[s]; }
        offs[NSLICE] = acc;
    }
    if (lane < NSLICE) cursor[lane] = 0;   // after offs written (in-wave order)

    float2* row  = ws + (size_t)b * ROW_F2;
    float2* prow = row + HDR_F2;

    // pass 2: recompute params, scatter bin-sorted into workspace
    for (int r = 0; r < NROUNDS; ++r) {
        int gi = r * 64 + lane;
        unsigned e = g_tbl.e[gi];
        int kzi = e & 31, kyi = (e >> 5) & 31, kxi = (e >> 10) & 31, order = (int)(e >> 15);
        float d   = sqrtf(dsq[kxi] + dsq[NK + kyi] + dsq[2 * NK + kzi]);
        float dly = 40.0f + d * FS_OVER_C;
        int   t0  = (int)floorf(dly);
        bool live = (gi < NIMG_TOTAL) && (t0 - HALF_W < T_LEN);
        if (live) {
            float amp = exp2f((float)order * LOG2_BETA) * INV_4PI_F
                        * __builtin_amdgcn_rcpf(fmaxf(d, 0.001f));
            int bin  = min(t0 / TS, NSLICE - 1);
            int rank = offs[bin] + atomicAdd(&cursor[bin], 1);
            prow[rank] = make_float2(amp, dly);
        }
    }

    // header: 55 offsets as ints
    int* hdr = (int*)row;
    if (lane <= NSLICE) hdr[lane] = offs[lane];
}

// ============ Kernel 2: 1-wave barrier-free slice scatter ===================
__global__ __launch_bounds__(64)
void rir_scatter_kernel(const float2* __restrict__ ws, float* __restrict__ out_rir)
{
    __shared__ __align__(16) float rirw[TS];     // 1792 B

    const int lane = threadIdx.x;
    const int s    = blockIdx.x;
    const int b    = blockIdx.y;
    const int lo   = s * TS;
    const int nout = min(TS, T_LEN - lo);        // 448, or 256 for slice 53

    const float2* row  = ws + (size_t)b * ROW_F2;
    const float2* prow = row + HDR_F2;
    const int*    hdr  = (const int*)row;

    // bins s-1..s+1 cover all images whose window touches this slice
    const int s0    = (s > 0) ? s - 1 : 0;
    const int s1    = (s < NSLICE - 1) ? s + 1 : NSLICE - 1;
    const int start = hdr[s0];
    const int end   = hdr[s1 + 1];

    float4* rir4 = (float4*)rirw;
    rir4[lane] = make_float4(0.f, 0.f, 0.f, 0.f);
    if (lane < TS / 4 - 64) rir4[64 + lane] = make_float4(0.f, 0.f, 0.f, 0.f);

    const float c1p = PI_F * (float)(lane - HALF_W);
    const float hw1 = 0.5f - 0.5f * __cosf((float)lane * (2.0f * PI_F / 80.0f));
    const float hw2 = 0.5f - 0.5f * __cosf((float)(lane + 64) * (2.0f * PI_F / 80.0f));
    const float sg  = (lane & 1) ? 1.0f : -1.0f;

    const float lof = (float)(lo - HALF_W);
    const float hif = (float)(lo + nout - 1 + HALF_W);

    for (int i0 = start + lane; i0 - lane < end; i0 += 64) {
        const bool inr = (i0 < end);
        float2 p = prow[inr ? i0 : start];       // batched coalesced load
        float t0f = floorf(p.y);
        bool hit  = inr && (t0f >= lof) && (t0f <= hif);
        float ampv = p.x, dlyv = p.y;

        unsigned long long mask = __ballot(hit);
        while (mask) {
            int l0 = __builtin_ctzll(mask); mask &= mask - 1;
            bool have1 = (mask != 0);
            int l1 = have1 ? __builtin_ctzll(mask) : l0;
            if (have1) mask &= mask - 1;

            float a0 = __shfl(ampv, l0), d0 = __shfl(dlyv, l0);
            float a1 = __shfl(ampv, l1), d1 = __shfl(dlyv, l1);
            PROCESS(a0, d0);
            if (have1) PROCESS(a1, d1);
        }
    }

    const int n4 = nout / 4;                     // 112 or 64
    float4* out4 = (float4*)(out_rir + (size_t)b * T_LEN + lo);
    out4[lane] = rir4[lane];
    if (lane + 64 < n4) out4[lane + 64] = rir4[lane + 64];
}

// ============ Fallback: R10 single-kernel (ws too small) ====================
__global__ __launch_bounds__(64)
void rir_wave_kernel(const float* __restrict__ g_in,
                     const float* __restrict__ W1, const float* __restrict__ b1,
                     const float* __restrict__ W2, const float* __restrict__ b2,
                     const float* __restrict__ W3, const float* __restrict__ b3,
                     float* __restrict__ out_rir, float* __restrict__ out_origin)
{
    __shared__ __align__(16) float rirw[TS];
    __shared__ float dsq[3 * NK];
    __shared__ float h1[30], h2[20], zb[9], sm_in[22], rms[9];

    const int lane = threadIdx.x;
    const int s    = blockIdx.x;
    const int b    = blockIdx.y;
    const int lo   = s * TS;
    const int nout = min(TS, T_LEN - lo);

    float4* rir4 = (float4*)rirw;
    rir4[lane] = make_float4(0.f, 0.f, 0.f, 0.f);
    if (lane < TS / 4 - 64) rir4[64 + lane] = make_float4(0.f, 0.f, 0.f, 0.f);

    const float c1p = PI_F * (float)(lane - HALF_W);
    const float hw1 = 0.5f - 0.5f * __cosf((float)lane * (2.0f * PI_F / 80.0f));
    const float hw2 = 0.5f - 0.5f * __cosf((float)(lane + 64) * (2.0f * PI_F / 80.0f));
    const float sg  = (lane & 1) ? 1.0f : -1.0f;

    if (lane < 22) sm_in[lane] = g_in[b * 22 + lane];
    if (lane < 30) {
        float a = b1[lane];
        const float* wp = W1 + lane * 22;
        #pragma unroll
        for (int i = 0; i < 22; ++i) a += sm_in[i] * wp[i];
        h1[lane] = (a >= 0.0f) ? a : NEG_SLOPE * a;
    }
    if (lane < 20) {
        float a = b2[lane];
        const float* wp = W2 + lane * 30;
        #pragma unroll
        for (int i = 0; i < 30; ++i) a += h1[i] * wp[i];
        h2[lane] = (a >= 0.0f) ? a : NEG_SLOPE * a;
    }
    if (lane < 9) {
        float a = b3[lane];
        const float* wp = W3 + lane * 20;
        #pragma unroll
        for (int i = 0; i < 20; ++i) a += h2[i] * wp[i];
        zb[lane] = 1.0f / (1.0f + __expf(-a));
    }
    if (lane < 3) {
        float room = zb[lane] * 20.0f;
        rms[lane]     = room;
        rms[3 + lane] = zb[3 + lane] * room;
        rms[6 + lane] = zb[6 + lane] * room;
    }
    if (lane == 0 && s == 0) {
        float dx = rms[3] - rms[6], dy = rms[4] - rms[7], dz = rms[5] - rms[8];
        out_origin[b] = 40.0f + FS_F * sqrtf(dx * dx + dy * dy + dz * dz) / C_F;
    }
    if (lane < 3 * NK) {
        int a  = lane / NK;
        int kk = (lane - a * NK) - MAXORD;
        float L = rms[a], src = rms[6 + a];
        float img = ((kk & 1) == 0) ? (float)kk * L + src : (float)(kk + 1) * L - src;
        float diff = img - rms[3 + a];
        dsq[lane] = diff * diff;
    }

    const float lof = (float)(lo - HALF_W);
    const float hif = (float)(lo + nout - 1 + HALF_W);

    for (int r = 0; r < NROUNDS; ++r) {
        unsigned e = g_tbl.e[r * 64 + lane];
        bool live  = (r * 64 + lane) < NIMG_TOTAL;
        int kzi = e & 31, kyi = (e >> 5) & 31, kxi = (e >> 10) & 31, order = (int)(e >> 15);
        float d    = sqrtf(dsq[kxi] + dsq[NK + kyi] + dsq[2 * NK + kzi]);
        float dlyv = 40.0f + d * FS_OVER_C;
        float t0f  = floorf(dlyv);
        float ampv = exp2f((float)order * LOG2_BETA) * INV_4PI_F
                     * __builtin_amdgcn_rcpf(fmaxf(d, 0.001f));
        bool hit = live && (t0f >= lof) && (t0f <= hif);

        unsigned long long mask = __ballot(hit);
        while (mask) {
            int l0 = __builtin_ctzll(mask); mask &= mask - 1;
            bool have1 = (mask != 0);
            int l1 = have1 ? __builtin_ctzll(mask) : l0;
            if (have1) mask &= mask - 1;

            float a0 = __shfl(ampv, l0), d0 = __shfl(dlyv, l0);
            float a1 = __shfl(ampv, l1), d1 = __shfl(dlyv, l1);
            PROCESS(a0, d0);
            if (have1) PROCESS(a1, d1);
        }
    }

    const int n4 = nout / 4;
    float4* out4 = (float4*)(out_rir + (size_t)b * T_LEN + lo);
    out4[lane] = rir4[lane];
    if (lane + 64 < n4) out4[lane + 64] = rir4[lane + 64];
}

extern "C" void kernel_launch(void* const* d_in, const int* in_sizes, int n_in,
                              void* d_out, int out_size, void* d_ws, size_t ws_size,
                              hipStream_t stream) {
    const float* g_in = (const float*)d_in[0];
    const float* W1   = (const float*)d_in[1];
    const float* b1   = (const float*)d_in[2];
    const float* W2   = (const float*)d_in[3];
    const float* b2   = (const float*)d_in[4];
    const float* W3   = (const float*)d_in[5];
    const float* b3   = (const float*)d_in[6];

    const int B = in_sizes[0] / 22;

    float* out_rir    = (float*)d_out;
    float* out_origin = out_rir + (size_t)B * T_LEN;

    const size_t need_ws = (size_t)B * ROW_F2 * sizeof(float2);   // 1.6384 MB @B=128

    if (ws_size >= need_ws) {
        float2* ws = (float2*)d_ws;
        rir_prep_kernel<<<B, 64, 0, stream>>>(
            g_in, W1, b1, W2, b2, W3, b3, ws, out_origin);
        dim3 grid2(NSLICE, B);
        rir_scatter_kernel<<<grid2, 64, 0, stream>>>(ws, out_rir);
    } else {
        dim3 grid(NSLICE, B);
        rir_wave_kernel<<<grid, 64, 0, stream>>>(
            g_in, W1, b1, W2, b2, W3, b3, out_rir, out_origin);
    }
}